// Round 1
// baseline (317.122 us; speedup 1.0000x reference)
//
#include <hip/hip_runtime.h>
#include <math.h>

// Problem constants
#define B     256
#define NI    1152
#define DI    8
#define NO    10
#define DOUT  16
#define F     160          // NO*DOUT
#define KTOT  9216         // NI*DI

// s_gemm config: M=B=256 (b), N=F=160 (o,d), K=9216 (i,k)
#define SK    144          // split-K chunks
#define BK    32           // k-tile
// per block: BM=64 rows, 2 k-tiles (64 k-elems), 128 threads, 16x5 acc/thread

// ws layout (float offsets)
#define OFF_W2 0                          // 9216*160      = 1474560
#define OFF_P  1474560                    // 144*256*160   = 5898240
#define OFF_G2 (1474560 + 5898240)        // 2*160*9216    = 2949120
#define OFF_B  (OFF_G2 + 2949120)         // 1152*10       = 11520
#define OFF_C  (OFF_B + 11520)            // 1152*10       = 11520
// total 10344960 floats = 41.4 MB

// ---------------------------------------------------------------------------
// W2[(i*8+k)*160 + (o*16+d)] = W[i][o][d][k]
__global__ void prep_w2(const float* __restrict__ W, float* __restrict__ W2) {
    int idx = blockIdx.x * 256 + threadIdx.x;
    if (idx >= NI * DI * F) return;
    int od = idx % F;
    int ik = idx / F;
    int i = ik >> 3, k = ik & 7;
    int o = od >> 4, d = od & 15;
    W2[idx] = W[((i * NO + o) * DOUT + d) * DI + k];
}

// ---------------------------------------------------------------------------
// P[sk][b][f] = sum_{k in chunk} x[b][k] * c[i(k),o(f)] * W2[k][f]
__global__ __launch_bounds__(128) void s_gemm(const float* __restrict__ x,
                                              const float* __restrict__ W2,
                                              const float* __restrict__ c,
                                              float* __restrict__ P,
                                              int uniform) {
    __shared__ __attribute__((aligned(16))) float XsT[BK][68];   // [k][b], padded
    __shared__ __attribute__((aligned(16))) float As[BK][F];

    const int tid  = threadIdx.x;
    const int brow = blockIdx.x;          // 0..3
    const int sk   = blockIdx.y;          // 0..143
    const int b0   = brow * 64;
    const int k0   = sk * 64;
    const int ty   = tid >> 5;            // 0..3 -> rows ty*16..+15
    const int tx   = tid & 31;            // cols tx + 32*j

    float acc[16][5];
#pragma unroll
    for (int u = 0; u < 16; u++)
#pragma unroll
        for (int j = 0; j < 5; j++) acc[u][j] = 0.f;

    for (int kt = 0; kt < 2; kt++) {
        const int kb = k0 + kt * BK;
        // --- stage X tile transposed: XsT[k][b] ---
        {
            int bl = tid >> 1;
            int kh = (tid & 1) * 16;
            const float* xp = x + (size_t)(b0 + bl) * KTOT + kb + kh;
            float tmp[16];
            float4 v0 = ((const float4*)xp)[0];
            float4 v1 = ((const float4*)xp)[1];
            float4 v2 = ((const float4*)xp)[2];
            float4 v3 = ((const float4*)xp)[3];
            tmp[0]=v0.x; tmp[1]=v0.y; tmp[2]=v0.z; tmp[3]=v0.w;
            tmp[4]=v1.x; tmp[5]=v1.y; tmp[6]=v1.z; tmp[7]=v1.w;
            tmp[8]=v2.x; tmp[9]=v2.y; tmp[10]=v2.z; tmp[11]=v2.w;
            tmp[12]=v3.x; tmp[13]=v3.y; tmp[14]=v3.z; tmp[15]=v3.w;
#pragma unroll
            for (int q = 0; q < 16; q++) XsT[kh + q][bl] = tmp[q];
        }
        // --- stage A tile = c .* W2 rows ---
        {
            int kl = tid >> 2;
            int cb = (tid & 3) * 40;
            int kg = kb + kl;
            int i  = kg >> 3;
            const float* wp = W2 + (size_t)kg * F + cb;
#pragma unroll
            for (int u = 0; u < 10; u++) {
                int col = cb + u * 4;
                float cv = uniform ? 0.1f : c[i * NO + (col >> 4)];
                float4 v = ((const float4*)wp)[u];
                As[kl][col + 0] = v.x * cv;
                As[kl][col + 1] = v.y * cv;
                As[kl][col + 2] = v.z * cv;
                As[kl][col + 3] = v.w * cv;
            }
        }
        __syncthreads();
#pragma unroll
        for (int kk = 0; kk < BK; kk++) {
            float xv[16];
#pragma unroll
            for (int u = 0; u < 4; u++) {
                float4 v = *((const float4*)&XsT[kk][ty * 16 + u * 4]);
                xv[u*4+0]=v.x; xv[u*4+1]=v.y; xv[u*4+2]=v.z; xv[u*4+3]=v.w;
            }
            float av[5];
#pragma unroll
            for (int j = 0; j < 5; j++) av[j] = As[kk][tx + 32 * j];
#pragma unroll
            for (int u = 0; u < 16; u++)
#pragma unroll
                for (int j = 0; j < 5; j++)
                    acc[u][j] = fmaf(xv[u], av[j], acc[u][j]);
        }
        __syncthreads();
    }
    float* Pp = P + ((size_t)sk * B + b0) * F;
#pragma unroll
    for (int u = 0; u < 16; u++)
#pragma unroll
        for (int j = 0; j < 5; j++)
            Pp[(ty * 16 + u) * F + tx + 32 * j] = acc[u][j];
}

// ---------------------------------------------------------------------------
// s[b][f] = squash_over_d( sum_sk P[sk][b][f] )
__global__ void reduce_squash(const float* __restrict__ P, float* __restrict__ sout) {
    int idx = blockIdx.x * 256 + threadIdx.x;   // 0..40959 = b*160 + o*16 + d
    float sum = 0.f;
    for (int sk = 0; sk < SK; sk++) sum += P[(size_t)sk * B * F + idx];
    float n2 = sum * sum;
#pragma unroll
    for (int off = 8; off > 0; off >>= 1) n2 += __shfl_xor(n2, off, 16);
    float l2 = sqrtf(n2);
    float scale = l2 / (1.f + n2);              // == (l2^2/(1+l2^2)) / l2
    sout[idx] = sum * scale;
}

// ---------------------------------------------------------------------------
// G2p[half][f][m] = sum_{b in half} s[b][f] * x[b][m]
__global__ __launch_bounds__(256) void g2c(const float* __restrict__ s,
                                           const float* __restrict__ x,
                                           float* __restrict__ G2p) {
    __shared__ __attribute__((aligned(16))) float Ss[BK][F];    // 20KB
    __shared__ __attribute__((aligned(16))) float Xs[BK][64];   // 8KB

    const int tid  = threadIdx.x;
    const int mc   = blockIdx.x;      // 0..143
    const int half = blockIdx.y;      // 0..1
    const int m0   = mc * 64;
    const int ty   = tid >> 5;        // 0..7  -> m = ty*8 + j
    const int tx   = tid & 31;        // f = tx + 32*a

    float acc[5][8];
#pragma unroll
    for (int a = 0; a < 5; a++)
#pragma unroll
        for (int j = 0; j < 8; j++) acc[a][j] = 0.f;

    for (int step = 0; step < 4; step++) {
        int bb = half * 128 + step * 32;
        {   // stage s tile [32][160]
            int row = tid >> 3, cb = (tid & 7) * 20;
            const float* sp = s + (size_t)(bb + row) * F + cb;
#pragma unroll
            for (int u = 0; u < 5; u++) {
                float4 v = ((const float4*)sp)[u];
                Ss[row][cb + u*4 + 0] = v.x;
                Ss[row][cb + u*4 + 1] = v.y;
                Ss[row][cb + u*4 + 2] = v.z;
                Ss[row][cb + u*4 + 3] = v.w;
            }
        }
        {   // stage x tile [32][64]
            int row = tid >> 3, col = (tid & 7) * 8;
            const float* xp = x + (size_t)(bb + row) * KTOT + m0 + col;
            float4 v0 = ((const float4*)xp)[0];
            float4 v1 = ((const float4*)xp)[1];
            Xs[row][col+0]=v0.x; Xs[row][col+1]=v0.y; Xs[row][col+2]=v0.z; Xs[row][col+3]=v0.w;
            Xs[row][col+4]=v1.x; Xs[row][col+5]=v1.y; Xs[row][col+6]=v1.z; Xs[row][col+7]=v1.w;
        }
        __syncthreads();
#pragma unroll
        for (int kk = 0; kk < BK; kk++) {
            float sv[5];
#pragma unroll
            for (int a = 0; a < 5; a++) sv[a] = Ss[kk][tx + 32 * a];
            float xv[8];
            float4 v0 = *((const float4*)&Xs[kk][ty * 8]);
            float4 v1 = *((const float4*)&Xs[kk][ty * 8 + 4]);
            xv[0]=v0.x; xv[1]=v0.y; xv[2]=v0.z; xv[3]=v0.w;
            xv[4]=v1.x; xv[5]=v1.y; xv[6]=v1.z; xv[7]=v1.w;
#pragma unroll
            for (int a = 0; a < 5; a++)
#pragma unroll
                for (int j = 0; j < 8; j++)
                    acc[a][j] = fmaf(sv[a], xv[j], acc[a][j]);
        }
        __syncthreads();
    }
#pragma unroll
    for (int a = 0; a < 5; a++) {
        int f = tx + 32 * a;
        float* gp = G2p + ((size_t)(half * F + f)) * KTOT + m0 + ty * 8;
        float4 w0 = make_float4(acc[a][0], acc[a][1], acc[a][2], acc[a][3]);
        float4 w1 = make_float4(acc[a][4], acc[a][5], acc[a][6], acc[a][7]);
        ((float4*)gp)[0] = w0;
        ((float4*)gp)[1] = w1;
    }
}

// ---------------------------------------------------------------------------
// t[i,o] = sum_{d,k} W[i,o,d,k] * (G2p[0]+G2p[1])[o*16+d][i*8+k];
// b += t; c = softmax(b) over o.
__global__ __launch_bounds__(320) void contract_softmax(const float* __restrict__ G2p,
                                                        const float* __restrict__ W,
                                                        float* __restrict__ blog,
                                                        float* __restrict__ c) {
    __shared__ float ts[32][NO];
    const int tid = threadIdx.x;          // 0..319
    const int i0  = blockIdx.x * 32;
    const int il  = tid / NO;
    const int o   = tid % NO;
    const int i   = i0 + il;

    float acc = 0.f;
    const float* wp = W + (size_t)(i * NO + o) * DOUT * DI;
#pragma unroll
    for (int d = 0; d < DOUT; d++) {
        const float* g0 = G2p + (size_t)(o * DOUT + d) * KTOT + i * DI;
        const float* g1 = g0 + (size_t)F * KTOT;
        float4 ga0 = ((const float4*)g0)[0];
        float4 ga1 = ((const float4*)g0)[1];
        float4 gb0 = ((const float4*)g1)[0];
        float4 gb1 = ((const float4*)g1)[1];
        float4 w0  = ((const float4*)(wp + d * DI))[0];
        float4 w1  = ((const float4*)(wp + d * DI))[1];
        acc += (ga0.x + gb0.x) * w0.x + (ga0.y + gb0.y) * w0.y +
               (ga0.z + gb0.z) * w0.z + (ga0.w + gb0.w) * w0.w;
        acc += (ga1.x + gb1.x) * w1.x + (ga1.y + gb1.y) * w1.y +
               (ga1.z + gb1.z) * w1.z + (ga1.w + gb1.w) * w1.w;
    }
    float bnew = blog[i * NO + o] + acc;
    blog[i * NO + o] = bnew;
    ts[il][o] = bnew;
    __syncthreads();
    if (tid < 32) {
        float m = -3.402823466e+38f;
#pragma unroll
        for (int oo = 0; oo < NO; oo++) m = fmaxf(m, ts[tid][oo]);
        float e[NO];
        float sum = 0.f;
#pragma unroll
        for (int oo = 0; oo < NO; oo++) { e[oo] = expf(ts[tid][oo] - m); sum += e[oo]; }
        float inv = 1.f / sum;
#pragma unroll
        for (int oo = 0; oo < NO; oo++) c[(i0 + tid) * NO + oo] = e[oo] * inv;
    }
}

// ---------------------------------------------------------------------------
extern "C" void kernel_launch(void* const* d_in, const int* in_sizes, int n_in,
                              void* d_out, int out_size, void* d_ws, size_t ws_size,
                              hipStream_t stream) {
    const float* x = (const float*)d_in[0];
    const float* W = (const float*)d_in[1];
    float* out = (float*)d_out;          // doubles as the s buffer
    float* ws  = (float*)d_ws;
    float* W2  = ws + OFF_W2;
    float* P   = ws + OFF_P;
    float* G2  = ws + OFF_G2;
    float* bl  = ws + OFF_B;
    float* cc  = ws + OFF_C;

    hipMemsetAsync(bl, 0, NI * NO * sizeof(float), stream);
    prep_w2<<<5760, 256, 0, stream>>>(W, W2);

    for (int r = 0; r < 4; r++) {
        s_gemm<<<dim3(4, SK), 128, 0, stream>>>(x, W2, cc, P, r == 0 ? 1 : 0);
        reduce_squash<<<160, 256, 0, stream>>>(P, out);
        if (r < 3) {
            g2c<<<dim3(144, 2), 256, 0, stream>>>(out, x, G2);
            contract_softmax<<<36, 320, 0, stream>>>(G2, W, bl, cc);
        }
    }
}

// Round 2
// 194.438 us; speedup vs baseline: 1.6310x; 1.6310x over previous
//
#include <hip/hip_runtime.h>
#include <math.h>

// Problem constants
#define B_    256
#define NI    1152
#define DI    8
#define NO    10
#define DOUT  16
#define F     160          // NO*DOUT
#define KTOT  9216         // NI*DI
#define SK    144          // split-K chunks for s-pass
#define BK    64           // k-tile

// ws layout (float offsets)
#define OFF_W2 0                         // 9216*160 = 1474560
#define OFF_P  1474560                   // 144*256*160 = 5898240
#define OFF_B  (OFF_P + 5898240)         // 1152*10
#define OFF_C  (OFF_B + 11520)           // 1152*10
#define OFF_T  (OFF_C + 11520)           // 8*1152*5 = 46080  (tpart[q*2+fy][i*5+j])

// ---------------------------------------------------------------------------
// W2[(i*8+k)*160 + (o*16+d)] = W[i][o][d][k]; also zero b-logits.
__global__ void prep_w2(const float* __restrict__ W, float* __restrict__ W2,
                        float* __restrict__ blog) {
    int idx = blockIdx.x * 256 + threadIdx.x;
    if (idx < NI * NO) blog[idx] = 0.f;
    if (idx >= NI * DI * F) return;
    int od = idx % F;
    int ik = idx / F;
    int i = ik >> 3, k = ik & 7;
    int o = od >> 4, d = od & 15;
    W2[idx] = W[((i * NO + o) * DOUT + d) * DI + k];
}

// ---------------------------------------------------------------------------
// P[sk][b][f] = sum_{k in chunk} x[b][k] * c[i(k),o(f)] * W2[k][f]
// tile: 128 b x 80 f x 64 k, 256 threads, acc 8x5
__global__ __launch_bounds__(256, 2) void s_gemm(const float* __restrict__ x,
                                                 const float* __restrict__ W2,
                                                 const float* __restrict__ c,
                                                 float* __restrict__ P,
                                                 int uniform) {
    __shared__ __attribute__((aligned(16))) float XsT[BK][132];  // [k][b], pad 4
    __shared__ __attribute__((aligned(16))) float As[BK][80];

    const int t  = threadIdx.x;
    const int b0 = (blockIdx.x & 1) * 128;
    const int f0 = (blockIdx.x >> 1) * 80;
    const int k0 = blockIdx.y * BK;

    // --- stage X tile transposed: XsT[k][b] ---
    {
        const int bl = t >> 1;
        const int kh = (t & 1) * 32;
        const float* xp = x + (size_t)(b0 + bl) * KTOT + k0 + kh;
        float4 v[8];
#pragma unroll
        for (int p = 0; p < 8; p++) v[p] = ((const float4*)xp)[p];
#pragma unroll
        for (int p = 0; p < 8; p++) {
            XsT[kh + p * 4 + 0][bl] = v[p].x;
            XsT[kh + p * 4 + 1][bl] = v[p].y;
            XsT[kh + p * 4 + 2][bl] = v[p].z;
            XsT[kh + p * 4 + 3][bl] = v[p].w;
        }
    }
    // --- stage A tile = c .* W2, linear float4 writes (conflict-free) ---
    {
#pragma unroll
        for (int p = 0; p < 5; p++) {
            int vid  = p * 256 + t;        // 0..1279
            int kl   = vid / 20;
            int colv = (vid % 20) * 4;     // float4 never crosses an o-boundary
            int i    = (k0 + kl) >> 3;
            int o    = (f0 + colv) >> 4;
            float cv = uniform ? 0.1f : c[i * NO + o];
            float4 w = *(const float4*)(W2 + (size_t)(k0 + kl) * F + f0 + colv);
            w.x *= cv; w.y *= cv; w.z *= cv; w.w *= cv;
            *(float4*)(&As[kl][colv]) = w;
        }
    }
    __syncthreads();

    const int tf = t & 15;     // f = f0 + tf + 16*j
    const int tb = t >> 4;     // b = b0 + tb*8 + u
    float acc[8][5];
#pragma unroll
    for (int u = 0; u < 8; u++)
#pragma unroll
        for (int j = 0; j < 5; j++) acc[u][j] = 0.f;

#pragma unroll 8
    for (int kk = 0; kk < BK; kk++) {
        float4 xa = *(const float4*)(&XsT[kk][tb * 8]);
        float4 xb = *(const float4*)(&XsT[kk][tb * 8 + 4]);
        float xv[8] = {xa.x, xa.y, xa.z, xa.w, xb.x, xb.y, xb.z, xb.w};
        float av[5];
#pragma unroll
        for (int j = 0; j < 5; j++) av[j] = As[kk][tf + 16 * j];
#pragma unroll
        for (int u = 0; u < 8; u++)
#pragma unroll
            for (int j = 0; j < 5; j++)
                acc[u][j] = fmaf(xv[u], av[j], acc[u][j]);
    }

    float* Pp = P + ((size_t)blockIdx.y * B_ + b0) * F + f0;
#pragma unroll
    for (int u = 0; u < 8; u++)
#pragma unroll
        for (int j = 0; j < 5; j++)
            Pp[(size_t)(tb * 8 + u) * F + tf + 16 * j] = acc[u][j];
}

// ---------------------------------------------------------------------------
// s[b][f] = squash_over_d( sum_sk P[sk][b][f] )
__global__ void reduce_squash(const float* __restrict__ P, float* __restrict__ sout) {
    int idx = blockIdx.x * 256 + threadIdx.x;   // b*160 + o*16 + d
    float sum = 0.f;
#pragma unroll 8
    for (int sk = 0; sk < SK; sk++) sum += P[(size_t)sk * B_ * F + idx];
    float n2 = sum * sum;
#pragma unroll
    for (int off = 8; off > 0; off >>= 1) n2 += __shfl_xor(n2, off, 16);
    float l2 = sqrtf(n2);
    float scale = l2 / (1.f + n2);
    sout[idx] = sum * scale;
}

// ---------------------------------------------------------------------------
// Fused agreement: GEMM C[f][m] = sum_{b in quarter} s[b][f]*x[b][m] kept in
// registers, contracted against W in the epilogue:
//   tpart[q*2+fy][i*5+j] = sum_{d,k,b in q} W[i, o, d, k] * s[b,o*16+d] * x[b,i*8+k]
// thread (tf,j,tm,u): d = tf, o = by*5+j, i = bx*16+tm, k = u. No atomics.
__global__ __launch_bounds__(256, 2) void g2c(const float* __restrict__ s,
                                              const float* __restrict__ x,
                                              const float* __restrict__ W,
                                              float* __restrict__ tpart) {
    __shared__ __attribute__((aligned(16))) float Ss[64][80];
    __shared__ __attribute__((aligned(16))) float Xs[64][132];

    const int t  = threadIdx.x;
    const int m0 = blockIdx.x * 128;   // 72 m-tiles
    const int f0 = blockIdx.y * 80;    // 2 f-tiles
    const int q  = blockIdx.z;         // 4 b-quarters
    const int b0 = q * 64;

    // stage s tile [64][80], linear float4
#pragma unroll
    for (int p = 0; p < 5; p++) {
        int vid  = p * 256 + t;
        int row  = vid / 20;
        int colv = (vid % 20) * 4;
        *(float4*)(&Ss[row][colv]) =
            *(const float4*)(s + (size_t)(b0 + row) * F + f0 + colv);
    }
    // stage x tile [64][128], linear float4
#pragma unroll
    for (int p = 0; p < 8; p++) {
        int vid = p * 256 + t;
        int fl  = vid * 4;
        int row = fl >> 7;
        int col = fl & 127;
        *(float4*)(&Xs[row][col]) =
            *(const float4*)(x + (size_t)(b0 + row) * KTOT + m0 + col);
    }
    __syncthreads();

    const int tf = t & 15;   // f = f0 + tf + 16*j  -> d = tf, o = by*5 + j
    const int tm = t >> 4;   // m = m0 + tm*8 + u   -> i = bx*16 + tm, k = u
    float acc[5][8];
#pragma unroll
    for (int j = 0; j < 5; j++)
#pragma unroll
        for (int u = 0; u < 8; u++) acc[j][u] = 0.f;

#pragma unroll 8
    for (int kk = 0; kk < 64; kk++) {
        float4 xa = *(const float4*)(&Xs[kk][tm * 8]);
        float4 xb = *(const float4*)(&Xs[kk][tm * 8 + 4]);
        float xv[8] = {xa.x, xa.y, xa.z, xa.w, xb.x, xb.y, xb.z, xb.w};
        float av[5];
#pragma unroll
        for (int j = 0; j < 5; j++) av[j] = Ss[kk][tf + 16 * j];
#pragma unroll
        for (int j = 0; j < 5; j++)
#pragma unroll
            for (int u = 0; u < 8; u++)
                acc[j][u] = fmaf(av[j], xv[u], acc[j][u]);
    }

    // epilogue: contract with W over (k=u) then shuffle-reduce over d (=tf)
    const int i = blockIdx.x * 16 + tm;
#pragma unroll
    for (int j = 0; j < 5; j++) {
        int o = blockIdx.y * 5 + j;
        const float* wp = W + ((size_t)(i * NO + o) * DOUT + tf) * DI;
        float4 w0 = ((const float4*)wp)[0];
        float4 w1 = ((const float4*)wp)[1];
        float dot = acc[j][0] * w0.x + acc[j][1] * w0.y +
                    acc[j][2] * w0.z + acc[j][3] * w0.w +
                    acc[j][4] * w1.x + acc[j][5] * w1.y +
                    acc[j][6] * w1.z + acc[j][7] * w1.w;
#pragma unroll
        for (int off = 8; off > 0; off >>= 1) dot += __shfl_xor(dot, off, 16);
        if (tf == 0)
            tpart[((size_t)(q * 2 + blockIdx.y) * NI + i) * 5 + j] = dot;
    }
}

// ---------------------------------------------------------------------------
// b += sum_q tpart; c = softmax(b) over o.
__global__ __launch_bounds__(320) void softmax_b(const float* __restrict__ tpart,
                                                 float* __restrict__ blog,
                                                 float* __restrict__ c) {
    __shared__ float ts[32][NO];
    const int t  = threadIdx.x;          // 0..319
    const int i0 = blockIdx.x * 32;
    const int il = t / NO;
    const int o  = t % NO;
    const int i  = i0 + il;

    const int fy = o / 5, j = o % 5;
    float acc = 0.f;
#pragma unroll
    for (int q = 0; q < 4; q++)
        acc += tpart[((size_t)(q * 2 + fy) * NI + i) * 5 + j];
    float bnew = blog[i * NO + o] + acc;
    blog[i * NO + o] = bnew;
    ts[il][o] = bnew;
    __syncthreads();
    if (t < 32) {
        float m = -3.402823466e+38f;
#pragma unroll
        for (int oo = 0; oo < NO; oo++) m = fmaxf(m, ts[t][oo]);
        float e[NO];
        float sum = 0.f;
#pragma unroll
        for (int oo = 0; oo < NO; oo++) { e[oo] = expf(ts[t][oo] - m); sum += e[oo]; }
        float inv = 1.f / sum;
#pragma unroll
        for (int oo = 0; oo < NO; oo++) c[(i0 + t) * NO + oo] = e[oo] * inv;
    }
}

// ---------------------------------------------------------------------------
extern "C" void kernel_launch(void* const* d_in, const int* in_sizes, int n_in,
                              void* d_out, int out_size, void* d_ws, size_t ws_size,
                              hipStream_t stream) {
    const float* x = (const float*)d_in[0];
    const float* W = (const float*)d_in[1];
    float* out = (float*)d_out;          // doubles as the s buffer
    float* ws  = (float*)d_ws;
    float* W2  = ws + OFF_W2;
    float* P   = ws + OFF_P;
    float* bl  = ws + OFF_B;
    float* cc  = ws + OFF_C;
    float* tp  = ws + OFF_T;

    prep_w2<<<5760, 256, 0, stream>>>(W, W2, bl);

    for (int r = 0; r < 4; r++) {
        s_gemm<<<dim3(4, SK), 256, 0, stream>>>(x, W2, cc, P, r == 0 ? 1 : 0);
        reduce_squash<<<160, 256, 0, stream>>>(P, out);
        if (r < 3) {
            g2c<<<dim3(72, 2, 4), 256, 0, stream>>>(out, x, W, tp);
            softmax_b<<<36, 320, 0, stream>>>(tp, bl, cc);
        }
    }
}

// Round 3
// 134.965 us; speedup vs baseline: 2.3497x; 1.4406x over previous
//
#include <hip/hip_runtime.h>
#include <math.h>

typedef __attribute__((ext_vector_type(8))) short bf16x8;
typedef __attribute__((ext_vector_type(4))) float f32x4;
typedef unsigned short u16;
typedef unsigned int u32;

#define NI    1152
#define DI    8
#define NO    10
#define DOUT  16
#define F     160
#define KTOT  9216
#define KS    288          // k-steps of 32 in s-gemm K
#define SK    144          // split-K blocks (2 k-steps = 64 each)

// ws float offsets
#define OFF_W2F 0                    // 1474560 f  (W2 fp32, frag-major)
#define OFF_WFH 1474560              // 737280 f (1474560 u16)
#define OFF_WFL 2211840
#define OFF_XFH 2949120              // 1179648 f (2359296 u16)
#define OFF_XFL 4128768
#define OFF_XTH 5308416
#define OFF_XTL 6488064
#define OFF_SFH 7667712              // 20480 f
#define OFF_SFL 7688192
#define OFF_P   7708672              // 144*256*160 = 5898240 f
#define OFF_B   13606912             // 11520
#define OFF_C   13618432             // 11520
#define OFF_T   13629952             // 2*11520
// total 13652992 f = 54.6 MB

union U8 { u16 u[8]; uint4 v; };

__device__ inline u16 bf16hi(float x) {
    u32 u = __float_as_uint(x);
    return (u16)((u + 0x7FFFu + ((u >> 16) & 1u)) >> 16);
}
__device__ inline float bf2f(u16 h) { return __uint_as_float(((u32)h) << 16); }

// ---------------------------------------------------------------------------
// One-time pack: W2f (fp32 frag-major), wf(0.1x) hi/lo, xf hi/lo, xt hi/lo, blog=0
__global__ void prep(const float* __restrict__ x, const float* __restrict__ W,
                     float* __restrict__ W2f, u16* __restrict__ wfh, u16* __restrict__ wfl,
                     u16* __restrict__ xfh, u16* __restrict__ xfl,
                     u16* __restrict__ xth, u16* __restrict__ xtl,
                     float* __restrict__ blog) {
    int gb = blockIdx.x;
    int t  = threadIdx.x;
    if (gb < 720) {                    // W2f + wf(0.1) + blog
        int tid = gb * 256 + t;        // 0..184319
        if (tid < NI * NO) blog[tid] = 0.f;
        int l = tid & 63, tmp = tid >> 6;          // tmp = ns*288 + ks
        int ks = tmp % KS, ns = tmp / KS;
        int i = ks * 4 + (l >> 4), o = ns, d = l & 15;
        const float* wp = W + ((size_t)(i * NO + o) * DOUT + d) * DI;
        float v[8];
        float4 a = ((const float4*)wp)[0], b = ((const float4*)wp)[1];
        v[0]=a.x; v[1]=a.y; v[2]=a.z; v[3]=a.w; v[4]=b.x; v[5]=b.y; v[6]=b.z; v[7]=b.w;
        float* dst = W2f + (size_t)tmp * 512 + l * 8;
        ((float4*)dst)[0] = a; ((float4*)dst)[1] = b;
        U8 ph, pl;
#pragma unroll
        for (int j = 0; j < 8; j++) {
            float p = 0.1f * v[j];
            u16 h = bf16hi(p);
            ph.u[j] = h; pl.u[j] = bf16hi(p - bf2f(h));
        }
        *(uint4*)(wfh + (size_t)tmp * 512 + l * 8) = ph.v;
        *(uint4*)(wfl + (size_t)tmp * 512 + l * 8) = pl.v;
    } else if (gb < 1872) {            // xf: A-frags for s-gemm
        int tid = (gb - 720) * 256 + t;   // 0..294911
        int l = tid & 63, tmp = tid >> 6;  // tmp = mt*288 + ks
        int ks = tmp % KS, mt = tmp / KS;
        const float* xp = x + (size_t)(mt * 16 + (l & 15)) * KTOT + ks * 32 + (l >> 4) * 8;
        float v[8];
        float4 a = ((const float4*)xp)[0], b = ((const float4*)xp)[1];
        v[0]=a.x; v[1]=a.y; v[2]=a.z; v[3]=a.w; v[4]=b.x; v[5]=b.y; v[6]=b.z; v[7]=b.w;
        U8 ph, pl;
#pragma unroll
        for (int j = 0; j < 8; j++) {
            u16 h = bf16hi(v[j]);
            ph.u[j] = h; pl.u[j] = bf16hi(v[j] - bf2f(h));
        }
        *(uint4*)(xfh + (size_t)tmp * 512 + l * 8) = ph.v;
        *(uint4*)(xfl + (size_t)tmp * 512 + l * 8) = pl.v;
    } else {                           // xt: B-frags for g2c (x transposed)
        int tid = (gb - 1872) * 256 + t;
        int l = tid & 63, tmp = tid >> 6;  // tmp = ns*8 + ks8
        int ks8 = tmp & 7, ns = tmp >> 3;  // ns 0..575
        U8 ph, pl;
#pragma unroll
        for (int j = 0; j < 8; j++) {
            float v = x[(size_t)(ks8 * 32 + (l >> 4) * 8 + j) * KTOT + ns * 16 + (l & 15)];
            u16 h = bf16hi(v);
            ph.u[j] = h; pl.u[j] = bf16hi(v - bf2f(h));
        }
        *(uint4*)(xth + (size_t)tmp * 512 + l * 8) = ph.v;
        *(uint4*)(xtl + (size_t)tmp * 512 + l * 8) = pl.v;
    }
}

// ---------------------------------------------------------------------------
// Per-round: wf = split(c .* W2f)
__global__ void cw2(const float* __restrict__ W2f, const float* __restrict__ c,
                    u16* __restrict__ wfh, u16* __restrict__ wfl) {
    int tid = blockIdx.x * 256 + threadIdx.x;
    int l = tid & 63, tmp = tid >> 6;
    int ks = tmp % KS, ns = tmp / KS;
    int i = ks * 4 + (l >> 4);
    float cv = c[i * NO + ns];
    const float* src = W2f + (size_t)tmp * 512 + l * 8;
    float v[8];
    float4 a = ((const float4*)src)[0], b = ((const float4*)src)[1];
    v[0]=a.x; v[1]=a.y; v[2]=a.z; v[3]=a.w; v[4]=b.x; v[5]=b.y; v[6]=b.z; v[7]=b.w;
    U8 ph, pl;
#pragma unroll
    for (int j = 0; j < 8; j++) {
        float p = cv * v[j];
        u16 h = bf16hi(p);
        ph.u[j] = h; pl.u[j] = bf16hi(p - bf2f(h));
    }
    *(uint4*)(wfh + (size_t)tmp * 512 + l * 8) = ph.v;
    *(uint4*)(wfl + (size_t)tmp * 512 + l * 8) = pl.v;
}

// ---------------------------------------------------------------------------
// P[sk][b][f] = sum_{k in 64-chunk} x[b][k]*(c.W2)[k][f]  via bf16 hi/lo MFMA
// wave tile 64(b) x 80(f); 1152 waves = 288 blocks
__global__ __launch_bounds__(256) void s_mfma(const u16* __restrict__ xfh, const u16* __restrict__ xfl,
                                              const u16* __restrict__ wfh, const u16* __restrict__ wfl,
                                              float* __restrict__ P) {
    const int t = threadIdx.x, l = t & 63, w = t >> 6;
    const int wid = blockIdx.x * 4 + w;
    const int sk = wid >> 3;
    const int rem = wid & 7;
    const int wm = rem >> 1;        // b-quarter (64 rows)
    const int wn = rem & 1;         // f-half (80 cols)

    f32x4 z = {0.f, 0.f, 0.f, 0.f};
    f32x4 acc[4][5];
#pragma unroll
    for (int m = 0; m < 4; m++)
#pragma unroll
        for (int n = 0; n < 5; n++) acc[m][n] = z;

#pragma unroll
    for (int kk = 0; kk < 2; kk++) {
        int ks = sk * 2 + kk;
        bf16x8 ah[4], al[4];
#pragma unroll
        for (int m = 0; m < 4; m++) {
            size_t fi = ((size_t)((wm * 4 + m) * KS + ks)) * 512 + l * 8;
            ah[m] = *(const bf16x8*)(xfh + fi);
            al[m] = *(const bf16x8*)(xfl + fi);
        }
#pragma unroll
        for (int n = 0; n < 5; n++) {
            size_t fi = ((size_t)((wn * 5 + n) * KS + ks)) * 512 + l * 8;
            bf16x8 bh = *(const bf16x8*)(wfh + fi);
            bf16x8 bl = *(const bf16x8*)(wfl + fi);
#pragma unroll
            for (int m = 0; m < 4; m++) {
                acc[m][n] = __builtin_amdgcn_mfma_f32_16x16x32_bf16(ah[m], bh, acc[m][n], 0, 0, 0);
                acc[m][n] = __builtin_amdgcn_mfma_f32_16x16x32_bf16(ah[m], bl, acc[m][n], 0, 0, 0);
                acc[m][n] = __builtin_amdgcn_mfma_f32_16x16x32_bf16(al[m], bh, acc[m][n], 0, 0, 0);
            }
        }
    }
    float* Pp = P + (size_t)sk * 40960;
    const int c0 = l & 15, rg = l >> 4;
#pragma unroll
    for (int m = 0; m < 4; m++) {
        int b = wm * 64 + m * 16 + rg * 4;
#pragma unroll
        for (int n = 0; n < 5; n++) {
            int f = wn * 80 + n * 16 + c0;
#pragma unroll
            for (int r = 0; r < 4; r++)
                Pp[(size_t)(b + r) * F + f] = acc[m][n][r];
        }
    }
}

// ---------------------------------------------------------------------------
// s = squash(sum_sk P); writes fp32 out + hi/lo A-frags for g2c
__global__ void reduce_squash(const float* __restrict__ P, float* __restrict__ sout,
                              u16* __restrict__ sfh, u16* __restrict__ sfl) {
    int idx = blockIdx.x * 256 + threadIdx.x;   // b*160 + f
    float sum = 0.f;
#pragma unroll 8
    for (int sk = 0; sk < SK; sk++) sum += P[(size_t)sk * 40960 + idx];
    float n2 = sum * sum;
#pragma unroll
    for (int off = 8; off > 0; off >>= 1) n2 += __shfl_xor(n2, off, 16);
    float l2 = sqrtf(n2);
    float scale = l2 / (1.f + n2);
    float sv = sum * scale;
    sout[idx] = sv;
    int b = idx / F, f = idx % F;
    u16 h = bf16hi(sv);
    u16 lo = bf16hi(sv - bf2f(h));
    size_t si = (size_t)((f >> 4) * 8 + (b >> 5)) * 512 + (((b >> 3) & 3) * 16 + (f & 15)) * 8 + (b & 7);
    sfh[si] = h; sfl[si] = lo;
}

// ---------------------------------------------------------------------------
// G[od][ik] = sum_{b in half} s[b][od]*x[b][ik] via MFMA (acc in regs),
// then epilogue contracts with W -> tpart[bh][i][o]  (complete, no atomics)
__global__ __launch_bounds__(256) void g_mfma(const u16* __restrict__ sfh, const u16* __restrict__ sfl,
                                              const u16* __restrict__ xth, const u16* __restrict__ xtl,
                                              const float* __restrict__ W, float* __restrict__ tpart) {
    __shared__ float G[160 * 68];
    const int t = threadIdx.x, l = t & 63, w = t >> 6;
    const int nb = blockIdx.x;      // 0..143 (64 ik cols)
    const int bhf = blockIdx.y;     // 0..1 (b half)
    const int wm = w & 1;           // od half (80)
    const int wn = w >> 1;          // ik sub (32)

    f32x4 z = {0.f, 0.f, 0.f, 0.f};
    f32x4 acc[5][2];
#pragma unroll
    for (int m = 0; m < 5; m++)
#pragma unroll
        for (int n = 0; n < 2; n++) acc[m][n] = z;

#pragma unroll
    for (int kst = 0; kst < 4; kst++) {
        int ks = bhf * 4 + kst;
        bf16x8 ah[5], al[5];
#pragma unroll
        for (int m = 0; m < 5; m++) {
            size_t fi = ((size_t)((wm * 5 + m) * 8 + ks)) * 512 + l * 8;
            ah[m] = *(const bf16x8*)(sfh + fi);
            al[m] = *(const bf16x8*)(sfl + fi);
        }
#pragma unroll
        for (int n = 0; n < 2; n++) {
            size_t fi = ((size_t)((nb * 4 + wn * 2 + n) * 8 + ks)) * 512 + l * 8;
            bf16x8 bh = *(const bf16x8*)(xth + fi);
            bf16x8 bl = *(const bf16x8*)(xtl + fi);
#pragma unroll
            for (int m = 0; m < 5; m++) {
                acc[m][n] = __builtin_amdgcn_mfma_f32_16x16x32_bf16(ah[m], bh, acc[m][n], 0, 0, 0);
                acc[m][n] = __builtin_amdgcn_mfma_f32_16x16x32_bf16(ah[m], bl, acc[m][n], 0, 0, 0);
                acc[m][n] = __builtin_amdgcn_mfma_f32_16x16x32_bf16(al[m], bh, acc[m][n], 0, 0, 0);
            }
        }
    }
    const int c0 = l & 15, rg = l >> 4;
#pragma unroll
    for (int m = 0; m < 5; m++)
#pragma unroll
        for (int n = 0; n < 2; n++)
#pragma unroll
            for (int r = 0; r < 4; r++)
                G[(wm * 80 + m * 16 + rg * 4 + r) * 68 + wn * 32 + n * 16 + c0] = acc[m][n][r];
    __syncthreads();
    if (t < 160) {
        int i_l = t / 20, o = (t % 20) >> 1, dh = t & 1;
        int i_g = nb * 8 + i_l;
        const float* wp = W + (size_t)(i_g * NO + o) * 128 + dh * 64;
        float sum = 0.f;
#pragma unroll
        for (int d = 0; d < 8; d++) {
            const float* gp = &G[(o * 16 + dh * 8 + d) * 68 + i_l * 8];
            float4 g0 = ((const float4*)gp)[0], g1 = ((const float4*)gp)[1];
            float4 w0 = ((const float4*)(wp + d * 8))[0], w1 = ((const float4*)(wp + d * 8))[1];
            sum += g0.x * w0.x + g0.y * w0.y + g0.z * w0.z + g0.w * w0.w +
                   g1.x * w1.x + g1.y * w1.y + g1.z * w1.z + g1.w * w1.w;
        }
        sum += __shfl_xor(sum, 1);
        if (dh == 0) tpart[bhf * 11520 + i_g * NO + o] = sum;
    }
}

// ---------------------------------------------------------------------------
// b += t; c = softmax(b) over o
__global__ __launch_bounds__(320) void softmax_b(const float* __restrict__ tpart,
                                                 float* __restrict__ blog,
                                                 float* __restrict__ c) {
    __shared__ float ts[32][NO];
    const int t = threadIdx.x;
    const int i0 = blockIdx.x * 32;
    const int il = t / NO, o = t % NO;
    const int i = i0 + il;
    float acc = tpart[i * NO + o] + tpart[11520 + i * NO + o];
    float bnew = blog[i * NO + o] + acc;
    blog[i * NO + o] = bnew;
    ts[il][o] = bnew;
    __syncthreads();
    if (t < 32) {
        float m = -3.402823466e+38f;
#pragma unroll
        for (int oo = 0; oo < NO; oo++) m = fmaxf(m, ts[t][oo]);
        float e[NO];
        float sum = 0.f;
#pragma unroll
        for (int oo = 0; oo < NO; oo++) { e[oo] = expf(ts[t][oo] - m); sum += e[oo]; }
        float inv = 1.f / sum;
#pragma unroll
        for (int oo = 0; oo < NO; oo++) c[(i0 + t) * NO + oo] = e[oo] * inv;
    }
}

// ---------------------------------------------------------------------------
extern "C" void kernel_launch(void* const* d_in, const int* in_sizes, int n_in,
                              void* d_out, int out_size, void* d_ws, size_t ws_size,
                              hipStream_t stream) {
    const float* x = (const float*)d_in[0];
    const float* W = (const float*)d_in[1];
    float* out = (float*)d_out;
    float* ws  = (float*)d_ws;
    float* W2f = ws + OFF_W2F;
    u16* wfh = (u16*)(ws + OFF_WFH);
    u16* wfl = (u16*)(ws + OFF_WFL);
    u16* xfh = (u16*)(ws + OFF_XFH);
    u16* xfl = (u16*)(ws + OFF_XFL);
    u16* xth = (u16*)(ws + OFF_XTH);
    u16* xtl = (u16*)(ws + OFF_XTL);
    u16* sfh = (u16*)(ws + OFF_SFH);
    u16* sfl = (u16*)(ws + OFF_SFL);
    float* P   = ws + OFF_P;
    float* bl  = ws + OFF_B;
    float* cc  = ws + OFF_C;
    float* tp  = ws + OFF_T;

    prep<<<3024, 256, 0, stream>>>(x, W, W2f, wfh, wfl, xfh, xfl, xth, xtl, bl);

    for (int r = 0; r < 4; r++) {
        if (r > 0) cw2<<<720, 256, 0, stream>>>(W2f, cc, wfh, wfl);
        s_mfma<<<288, 256, 0, stream>>>(xfh, xfl, wfh, wfl, P);
        reduce_squash<<<160, 256, 0, stream>>>(P, out, sfh, sfl);
        if (r < 3) {
            g_mfma<<<dim3(144, 2), 256, 0, stream>>>(sfh, sfl, xth, xtl, W, tp);
            softmax_b<<<36, 320, 0, stream>>>(tp, bl, cc);
        }
    }
}